// Round 7
// baseline (324.199 us; speedup 1.0000x reference)
//
#include <hip/hip_runtime.h>
#include <hip/hip_bf16.h>
#include <stdint.h>

#define USER_DIM 3706
#define ITEM_DIM 6040
#define LATENT   512
#define BATCH    8192
#define XCOLS    (USER_DIM + ITEM_DIM)   // 9746
#define KPAD_U   3712                     // 116 * 32
#define KPAD_I   6080                     // 190 * 32 (two halves of 95 steps)

typedef float f32x4 __attribute__((ext_vector_type(4)));
typedef short bf16x8 __attribute__((ext_vector_type(8)));

#define VMCNT(n) asm volatile("s_waitcnt vmcnt(" #n ")" ::: "memory")

static __device__ __forceinline__ unsigned short f2bf(float f) {
    union { float f; unsigned int u; } v; v.f = f;
    unsigned int u = v.u;
    u += 0x7fffu + ((u >> 16) & 1u);   // RNE (finite inputs)
    return (unsigned short)(u >> 16);
}
static __device__ __forceinline__ float bf2f(unsigned int b) {
    union { unsigned int u; float f; } v; v.u = b << 16; return v.f;
}
static __device__ __forceinline__ short cvt1(float f) {
    union { __hip_bfloat16 h; unsigned short u; } cv;
    cv.h = __float2bfloat16(f);
    return (short)cv.u;
}
static __device__ __forceinline__ bf16x8 cvt8(f32x4 lo, f32x4 hi) {
    bf16x8 r;
    #pragma unroll
    for (int i = 0; i < 4; ++i) { r[i] = cvt1(lo[i]); r[4 + i] = cvt1(hi[i]); }
    return r;
}
static __device__ __forceinline__ void gload16(const void* g, void* l) {
    __builtin_amdgcn_global_load_lds(
        (const __attribute__((address_space(1))) void*)g,
        (__attribute__((address_space(3))) void*)l, 16, 0, 0);
}
static __device__ __forceinline__ void BARRIER() {
    __builtin_amdgcn_sched_barrier(0);
    __builtin_amdgcn_s_barrier();
    __builtin_amdgcn_sched_barrier(0);
}

// ---- Kernel 1: weight fp32 -> bf16, zero-padded K ----
__global__ void convert_w(const float* __restrict__ W, unsigned short* __restrict__ Wb,
                          int K, int Kpad) {
    int c = blockIdx.x * blockDim.x + threadIdx.x;
    int r = blockIdx.y;
    if (c >= Kpad) return;
    unsigned short o = 0;
    if (c < K) o = f2bf(W[(size_t)r * K + c]);
    Wb[(size_t)r * Kpad + c] = o;
}

// ---- Kernel 2: fused towers. 128x128 tile, BK=32.
// A: DIRECT global->reg (per-wave MFMA fragments, no LDS), cvt 1 iter in flight.
// B: LDS via global_load_lds, 4-deep ring, ONE barrier + counted vmcnt per step.
// B LDS layout (r6, 0-conflict): [64 segs][128B]; (row r, chunk g) at
// seg=r>>1, c8=((r&1)*4+g)^(seg&7). Linear DMA dest, swizzle on source+read.
__global__ __launch_bounds__(256, 3) void gemm_fused(
    const float* __restrict__ X,
    const unsigned short* __restrict__ WuB, const float* __restrict__ bu,
    const unsigned short* __restrict__ WiB,
    unsigned short* __restrict__ Uemb,
    unsigned short* __restrict__ P0, unsigned short* __restrict__ P1)
{
    __shared__ unsigned short sB4[4][64 * 64];   // 4 x 8 KB bf16

    const int tid  = threadIdx.x;
    const int lane = tid & 63;
    const int wid  = tid >> 6;
    const int wm   = wid >> 1;
    const int wn   = wid & 1;

    // XCD-chunked bijective swizzle over 768 blocks (= 8 * 96);
    // 4 consecutive swz share an A-panel on one XCD.
    const int bid = blockIdx.x;
    const int swz = (bid & 7) * 96 + (bid >> 3);
    const int g4  = swz >> 2;          // 0..191
    const int nb  = swz & 3;

    // balanced tower interleave: per CU 1 user (116 steps) + 2 item halves (95)
    int mb, k0, nt, xoff, Kpad;
    const unsigned short* WB;
    bool isUser; int kh = 0;
    if (g4 % 3 == 0) {
        isUser = true;  mb = g4 / 3;
        k0 = 0; nt = KPAD_U / 32; xoff = 0; Kpad = KPAD_U; WB = WuB;
    } else {
        const int q = g4 - (g4 / 3 + 1);     // 0..127 bijective
        isUser = false; mb = q >> 1; kh = q & 1;
        k0 = kh * 95; nt = 95; xoff = USER_DIM; Kpad = KPAD_I; WB = WiB;
    }

    // ---- B staging lane geometry ----
    const int l8  = lane >> 3;                 // seg within issue
    const int c8w = lane & 7;                  // LDS chunk this lane fills
    const int s8  = c8w ^ l8;                  // source-side swizzled chunk
    const int spr = s8 >> 2;                   // source row parity
    const int skc = (s8 & 3) * 8;              // source k-col (elements)

    auto ISSUE_B = [&](int t, int buf) {
        const int kb = t * 32;
        unsigned short* sB = sB4[buf];
        #pragma unroll
        for (int j = 0; j < 2; ++j) {
            const int i  = wid * 2 + j;                // 0..7
            const int rt = (i * 8 + l8) * 2 + spr;     // tile row
            const unsigned short* s =
                WB + (size_t)(nb * 128 + rt) * Kpad + kb + skc;
            gload16(s, sB + i * 512);                  // linear 1KB dest
        }
    };

    // ---- A direct-load geometry: frag mi rows = mb*128+wm*64+mi*16+fr ----
    const int fr = lane & 15;
    const int g  = lane >> 4;
    const float* pA0 = X + (size_t)(mb * 128 + wm * 64 + 0  * 16 + fr) * XCOLS;
    const float* pA1 = X + (size_t)(mb * 128 + wm * 64 + 1  * 16 + fr) * XCOLS;
    const float* pA2 = X + (size_t)(mb * 128 + wm * 64 + 2  * 16 + fr) * XCOLS;
    const float* pA3 = X + (size_t)(mb * 128 + wm * 64 + 3  * 16 + fr) * XCOLS;

    f32x4 rafl[4], rafh[4];    // A fp32 landing regs (static-indexed only)
    bf16x8 af[4];              // A bf16 fragments for current tile

    auto ALOAD = [&](int t) {
        int kidx = xoff + t * 32 + g * 8;
        if (kidx > XCOLS - 8) kidx = XCOLS - 8;    // item tail clamp (junk x 0-B)
        rafl[0] = *(const f32x4*)(pA0 + kidx); rafh[0] = *(const f32x4*)(pA0 + kidx + 4);
        rafl[1] = *(const f32x4*)(pA1 + kidx); rafh[1] = *(const f32x4*)(pA1 + kidx + 4);
        rafl[2] = *(const f32x4*)(pA2 + kidx); rafh[2] = *(const f32x4*)(pA2 + kidx + 4);
        rafl[3] = *(const f32x4*)(pA3 + kidx); rafh[3] = *(const f32x4*)(pA3 + kidx + 4);
    };
    auto ACVT = [&]() {
        #pragma unroll
        for (int mi = 0; mi < 4; ++mi) af[mi] = cvt8(rafl[mi], rafh[mi]);
    };

    // ---- B fragment read geometry (0-conflict in r6) ----
    const int rc8 = ((((fr & 1) * 4) + g) ^ (fr >> 1)) * 8;
    const int bro = (wn * 32 + (fr >> 1)) * 64 + rc8;        // + ni*512

    f32x4 acc[4][4];
    #pragma unroll
    for (int i = 0; i < 4; ++i)
        #pragma unroll
        for (int j = 0; j < 4; ++j) acc[i][j] = (f32x4)0.0f;

    auto COMPUTE = [&](int buf) {
        const unsigned short* sB = sB4[buf];
        bf16x8 bfr[4];
        #pragma unroll
        for (int ni = 0; ni < 4; ++ni)
            bfr[ni] = *(const bf16x8*)(sB + bro + ni * 512);
        __builtin_amdgcn_s_setprio(1);
        #pragma unroll
        for (int mi = 0; mi < 4; ++mi)
            #pragma unroll
            for (int ni = 0; ni < 4; ++ni)
                acc[mi][ni] = __builtin_amdgcn_mfma_f32_16x16x32_bf16(
                    af[mi], bfr[ni], acc[mi][ni], 0, 0, 0);
        __builtin_amdgcn_s_setprio(0);
    };

    // ---- prologue ----
    ALOAD(k0);                   // A(0) -> raf          [8 vm]
    ISSUE_B(k0, 0);              // B(0) -> lds0         [2 vm]
    ACVT();                      // af = A(0)  (implicit vmcnt(2), B(0) in flight)
    ALOAD(k0 + 1);               // A(1) -> raf          [+8]
    ISSUE_B(k0 + 1, 1);          // B(1) -> lds1         [+2 = 12]
    VMCNT(10);                   // retire B(0)
    BARRIER();

    // ---- main loop: ONE barrier per K-step, all waits counted ----
    for (int t = 0; t < nt - 2; ++t) {
        COMPUTE(t & 3);          // tile t: af(t) x B LDS ring
        ACVT();                  // af = A(t+1)  (implicit vmcnt(2))
        ALOAD(k0 + t + 2);       // A(t+2) -> raf
        ISSUE_B(k0 + t + 2, (t + 2) & 3);
        VMCNT(10);               // retire B(t+1); A(t+2)+B(t+2) stay in flight
        BARRIER();               // ring slot (t+1)%4 published
    }
    // ---- tail: tiles nt-2, nt-1 ----
    COMPUTE((nt - 2) & 3);
    ACVT();                      // af = A(nt-1)
    VMCNT(0);                    // drain B(nt-1)
    BARRIER();
    COMPUTE((nt - 1) & 3);

    // ---- epilogue ----
    const int cb = nb * 128 + wn * 64;
    const int rb = mb * 128 + wm * 64 + (lane >> 4) * 4;
    if (isUser) {
        #pragma unroll
        for (int ni = 0; ni < 4; ++ni) {
            const int col = cb + ni * 16 + fr;
            const float bv = bu[col];
            #pragma unroll
            for (int mi = 0; mi < 4; ++mi) {
                f32x4 v = acc[mi][ni];
                #pragma unroll
                for (int r = 0; r < 4; ++r) {
                    const int row = rb + mi * 16 + r;
                    Uemb[(size_t)row * LATENT + col] = f2bf(fmaxf(v[r] + bv, 0.0f));
                }
            }
        }
    } else {
        unsigned short* P = kh ? P1 : P0;
        #pragma unroll
        for (int ni = 0; ni < 4; ++ni) {
            const int col = cb + ni * 16 + fr;
            #pragma unroll
            for (int mi = 0; mi < 4; ++mi) {
                f32x4 v = acc[mi][ni];
                #pragma unroll
                for (int r = 0; r < 4; ++r) {
                    const int row = rb + mi * 16 + r;
                    P[(size_t)row * LATENT + col] = f2bf(v[r]);   // partial
                }
            }
        }
    }
}

// ---- Kernel 3: out[b] = sum_d U[b,d] * relu(P0[b,d] + P1[b,d] + bi[d]) ----
__global__ void rowdot(const unsigned short* __restrict__ U,
                       const unsigned short* __restrict__ P0,
                       const unsigned short* __restrict__ P1,
                       const float* __restrict__ bi,
                       float* __restrict__ out) {
    const int lane = threadIdx.x & 63;
    const int w    = threadIdx.x >> 6;
    const int row  = blockIdx.x * 4 + w;
    const size_t base = (size_t)row * LATENT + lane * 8;
    const uint4 uv = *(const uint4*)(U  + base);
    const uint4 p0 = *(const uint4*)(P0 + base);
    const uint4 p1 = *(const uint4*)(P1 + base);
    const float4 b0 = *(const float4*)(bi + lane * 8);
    const float4 b1 = *(const float4*)(bi + lane * 8 + 4);
    const float bb[8] = {b0.x, b0.y, b0.z, b0.w, b1.x, b1.y, b1.z, b1.w};
    const unsigned int* up = (const unsigned int*)&uv;
    const unsigned int* q0 = (const unsigned int*)&p0;
    const unsigned int* q1 = (const unsigned int*)&p1;
    float acc = 0.0f;
    #pragma unroll
    for (int q = 0; q < 4; ++q) {
        float ilo = fmaxf(bf2f(q0[q] & 0xffffu) + bf2f(q1[q] & 0xffffu) + bb[2 * q], 0.0f);
        float ihi = fmaxf(bf2f(q0[q] >> 16)     + bf2f(q1[q] >> 16)     + bb[2 * q + 1], 0.0f);
        acc += bf2f(up[q] & 0xffffu) * ilo;
        acc += bf2f(up[q] >> 16)     * ihi;
    }
    #pragma unroll
    for (int off = 32; off >= 1; off >>= 1)
        acc += __shfl_xor(acc, off, 64);
    if (lane == 0) out[row] = acc;
}

extern "C" void kernel_launch(void* const* d_in, const int* in_sizes, int n_in,
                              void* d_out, int out_size, void* d_ws, size_t ws_size,
                              hipStream_t stream) {
    const float* x  = (const float*)d_in[0];
    const float* Wu = (const float*)d_in[1];
    const float* bu = (const float*)d_in[2];
    const float* Wi = (const float*)d_in[3];
    const float* bi = (const float*)d_in[4];
    float* out = (float*)d_out;

    unsigned short* WuB  = (unsigned short*)d_ws;                 // 512*3712 bf16
    unsigned short* WiB  = WuB + (size_t)LATENT * KPAD_U;         // 512*6080 bf16
    unsigned short* Uemb = WiB + (size_t)LATENT * KPAD_I;         // 8192*512 bf16
    unsigned short* P0   = Uemb + (size_t)BATCH * LATENT;         // 8192*512 bf16
    unsigned short* P1   = P0   + (size_t)BATCH * LATENT;         // 8192*512 bf16

    convert_w<<<dim3((KPAD_U + 255) / 256, LATENT), 256, 0, stream>>>(Wu, WuB, USER_DIM, KPAD_U);
    convert_w<<<dim3((KPAD_I + 255) / 256, LATENT), 256, 0, stream>>>(Wi, WiB, ITEM_DIM, KPAD_I);

    // 768 blocks = 3 per CU co-resident; 1 user + 2 item halves per CU.
    gemm_fused<<<768, 256, 0, stream>>>(x, WuB, bu, WiB, Uemb, P0, P1);

    rowdot<<<BATCH / 4, 256, 0, stream>>>(Uemb, P0, P1, bi, out);
}

// Round 8
// 259.120 us; speedup vs baseline: 1.2512x; 1.2512x over previous
//
#include <hip/hip_runtime.h>
#include <hip/hip_bf16.h>
#include <stdint.h>

#define USER_DIM 3706
#define ITEM_DIM 6040
#define LATENT   512
#define BATCH    8192
#define XCOLS    (USER_DIM + ITEM_DIM)   // 9746
#define KPAD_U   3712                     // 116 * 32
#define KPAD_I   6144                     // 192 * 32 (three thirds of 64 steps)

typedef float f32x4 __attribute__((ext_vector_type(4)));
typedef short bf16x8 __attribute__((ext_vector_type(8)));

#define VMCNT(n) asm volatile("s_waitcnt vmcnt(" #n ")" ::: "memory")
#define LGKM0    do { asm volatile("s_waitcnt lgkmcnt(0)" ::: "memory"); \
                      __builtin_amdgcn_sched_barrier(0); } while (0)

static __device__ __forceinline__ unsigned short f2bf(float f) {
    union { float f; unsigned int u; } v; v.f = f;
    unsigned int u = v.u;
    u += 0x7fffu + ((u >> 16) & 1u);   // RNE (finite inputs)
    return (unsigned short)(u >> 16);
}
static __device__ __forceinline__ float bf2f(unsigned int b) {
    union { unsigned int u; float f; } v; v.u = b << 16; return v.f;
}
static __device__ __forceinline__ void gload16(const void* g, void* l) {
    __builtin_amdgcn_global_load_lds(
        (const __attribute__((address_space(1))) void*)g,
        (__attribute__((address_space(3))) void*)l, 16, 0, 0);
}
static __device__ __forceinline__ void BARRIER() {
    __builtin_amdgcn_sched_barrier(0);
    __builtin_amdgcn_s_barrier();
    __builtin_amdgcn_sched_barrier(0);
}

// ---- Kernel 1: weight fp32 -> bf16, zero-padded K ----
__global__ void convert_w(const float* __restrict__ W, unsigned short* __restrict__ Wb,
                          int K, int Kpad) {
    int c = blockIdx.x * blockDim.x + threadIdx.x;
    int r = blockIdx.y;
    if (c >= Kpad) return;
    unsigned short o = 0;
    if (c < K) o = f2bf(W[(size_t)r * K + c]);
    Wb[(size_t)r * Kpad + c] = o;
}

// ---- Kernel 2: fused towers. 256x256 tile, 512 thr / 8 waves (2M x 4N),
// per-wave 128x64 (8x4 frags). BK=32, double-buffered, 2 phases per K-step.
// A: reg-staged (2-deep named sets) with write-side fp32->bf16 cvt.
// B: global_load_lds, source pre-swizzled, linear LDS dest.
// LDS layout (A,B identical, proven 0-conflict): [128 segs][128B];
// (row r, 16B-chunk g) at seg=r>>1, c8=((r&1)*4+g)^(seg&7).
__global__ __launch_bounds__(512, 2) void gemm_fused(
    const float* __restrict__ X,
    const unsigned short* __restrict__ WuB, const float* __restrict__ bu,
    const unsigned short* __restrict__ WiB,
    unsigned short* __restrict__ Uemb,
    unsigned short* __restrict__ P0, unsigned short* __restrict__ P1,
    unsigned short* __restrict__ P2)
{
    __shared__ unsigned short sA2[2][128 * 64];   // 2 x 16 KB bf16
    __shared__ unsigned short sB2[2][128 * 64];   // 2 x 16 KB bf16

    const int tid  = threadIdx.x;
    const int lane = tid & 63;
    const int wid  = tid >> 6;        // 0..7
    const int wmm  = wid >> 2;        // 0..1  (M half, 128 rows)
    const int wnn  = wid & 3;         // 0..3  (N quarter, 64 cols)

    // XCD-chunked swizzle over 256 blocks (8 x 32). Group of 4 = {user, 3 item thirds}
    const int bid = blockIdx.x;
    const int swz = (bid & 7) * 32 + (bid >> 3);
    const int u2  = swz >> 2;         // 0..63
    const int r4  = swz & 3;          // 0 = user, 1..3 = item third

    const int mb = u2 >> 1;           // 0..31
    const int nb = u2 & 1;            // 0..1
    int k0, nt, xoff, Kpad; const unsigned short* WB; bool isUser; int kth = 0;
    if (r4 == 0) { isUser = true;  k0 = 0; nt = KPAD_U / 32; xoff = 0;
                   Kpad = KPAD_U; WB = WuB; }
    else         { isUser = false; kth = r4 - 1; k0 = kth * 64; nt = 64;
                   xoff = USER_DIM; Kpad = KPAD_I; WB = WiB; }

    // ---- staging lane geometry ----
    const int l8  = lane >> 3;                 // seg within 8-seg group
    const int c8w = lane & 7;                  // LDS chunk this lane fills
    const int s8  = c8w ^ l8;                  // source-side swizzled chunk
    const int spr = s8 >> 2;                   // source row parity
    const int skc = (s8 & 3) * 8;              // source k-col (elements)

    // A: 256 rows x 32 k fp32 = 32 KB/step; thread: 2 ops x (2 f32x4 load, 1 b128 write)
    const int asg0 = wid * 16 + l8;            // op0 seg
    const int asg1 = asg0 + 8;                 // op1 seg
    const float* aptr0 = X + (size_t)(mb * 256 + asg0 * 2 + spr) * XCOLS + xoff;
    const float* aptr1 = X + (size_t)(mb * 256 + asg1 * 2 + spr) * XCOLS + xoff;

    auto ALOAD = [&](f32x4* R, int t) {
        int xc = t * 32 + skc;
        if (xoff + xc + 8 > XCOLS) xc = XCOLS - xoff - 8;   // tail clamp: junk x 0-B
        R[0] = *(const f32x4*)(aptr0 + xc);
        R[1] = *(const f32x4*)(aptr0 + xc + 4);
        R[2] = *(const f32x4*)(aptr1 + xc);
        R[3] = *(const f32x4*)(aptr1 + xc + 4);
    };
    auto AWRITE = [&](const f32x4* R, int buf) {
        unsigned short* sA = sA2[buf];
        uint4 w0, w1;
        w0.x = (unsigned)f2bf(R[0].x) | ((unsigned)f2bf(R[0].y) << 16);
        w0.y = (unsigned)f2bf(R[0].z) | ((unsigned)f2bf(R[0].w) << 16);
        w0.z = (unsigned)f2bf(R[1].x) | ((unsigned)f2bf(R[1].y) << 16);
        w0.w = (unsigned)f2bf(R[1].z) | ((unsigned)f2bf(R[1].w) << 16);
        w1.x = (unsigned)f2bf(R[2].x) | ((unsigned)f2bf(R[2].y) << 16);
        w1.y = (unsigned)f2bf(R[2].z) | ((unsigned)f2bf(R[2].w) << 16);
        w1.z = (unsigned)f2bf(R[3].x) | ((unsigned)f2bf(R[3].y) << 16);
        w1.w = (unsigned)f2bf(R[3].z) | ((unsigned)f2bf(R[3].w) << 16);
        *(uint4*)(sA + asg0 * 64 + c8w * 8) = w0;
        *(uint4*)(sA + asg1 * 64 + c8w * 8) = w1;
    };
    // B: 256 rows x 32 k bf16 = 16 KB/step; 16 DMA issues of 1 KB (2/wave)
    auto ISSUE_B = [&](int t, int buf) {
        const int kb = t * 32;
        unsigned short* sB = sB2[buf];
        #pragma unroll
        for (int j = 0; j < 2; ++j) {
            const int i  = wid * 2 + j;                // 0..15
            const int rt = (i * 8 + l8) * 2 + spr;     // B tile row 0..255
            const unsigned short* s =
                WB + (size_t)(nb * 256 + rt) * Kpad + kb + skc;
            gload16(s, sB + i * 512);                  // linear 1KB dest
        }
    };

    // ---- fragment read geometry (proven 0-conflict scheme) ----
    const int fr  = lane & 15;
    const int g   = lane >> 4;
    const int lro = (fr >> 1) * 64 + ((((fr & 1) * 4) + g) ^ (fr >> 1)) * 8;
    const int abase = wmm * 4096 + lro;        // + mi*512
    const int bbase = wnn * 2048 + lro;        // + ni*512

    f32x4 acc[8][4];
    #pragma unroll
    for (int i = 0; i < 8; ++i)
        #pragma unroll
        for (int j = 0; j < 4; ++j) acc[i][j] = (f32x4)0.0f;

    bf16x8 bfr[4];
    auto RD_B = [&](int buf) {
        const unsigned short* sB = sB2[buf];
        #pragma unroll
        for (int ni = 0; ni < 4; ++ni)
            bfr[ni] = *(const bf16x8*)(sB + bbase + ni * 512);
    };
    auto HALF = [&](int buf, int mi0) {        // read 4 A frags + 16 MFMA
        const unsigned short* sA = sA2[buf];
        bf16x8 af[4];
        #pragma unroll
        for (int q = 0; q < 4; ++q)
            af[q] = *(const bf16x8*)(sA + abase + (mi0 + q) * 512);
        __builtin_amdgcn_s_setprio(1);
        #pragma unroll
        for (int q = 0; q < 4; ++q)
            #pragma unroll
            for (int ni = 0; ni < 4; ++ni)
                acc[mi0 + q][ni] = __builtin_amdgcn_mfma_f32_16x16x32_bf16(
                    af[q], bfr[ni], acc[mi0 + q][ni], 0, 0, 0);
        __builtin_amdgcn_s_setprio(0);
    };

    f32x4 rA0[4], rA1[4];                      // 2-deep A reg sets (named)

    // ---- prologue ----
    ALOAD(rA0, k0);                 // A(0)              [4 vm]
    ISSUE_B(k0, 0);                 // B(0) -> buf0      [2 vm]
    ALOAD(rA1, k0 + 1);             // A(1)              [4 vm]
    AWRITE(rA0, 0);                 // implicit vmcnt(6) waits A(0)
    LGKM0;
    VMCNT(4);                       // retire B(0); A(1) stays in flight
    BARRIER();

    // ---- main loop: 2 phases/step, 2-step unroll for static reg-set parity ----
    #define STEP(T, CUR, RLD, RWR)                                         \
    {                                                                      \
        const int t_ = (T);                                                \
        /* Phase 0 */                                                      \
        RD_B(CUR);                                                         \
        if (t_ + 1 < nt) ISSUE_B(k0 + t_ + 1, (CUR) ^ 1);                  \
        BARRIER();                                                         \
        HALF(CUR, 0);                                                      \
        BARRIER();                                                         \
        /* Phase 1 */                                                      \
        if (t_ + 2 < nt) ALOAD(RLD, k0 + t_ + 2);                          \
        if (t_ + 1 < nt) AWRITE(RWR, (CUR) ^ 1);  /* waits A(t+1) */       \
        HALF(CUR, 4);                                                      \
        LGKM0;                                                             \
        if (t_ + 2 < nt)      { VMCNT(4); }      /* retire B(t+1) */       \
        else if (t_ + 1 < nt) { VMCNT(0); }                                \
        BARRIER();                                                         \
    }

    for (int t = 0; t < nt; t += 2) {          // nt even (116 / 64)
        STEP(t,     0, rA0, rA1)
        STEP(t + 1, 1, rA1, rA0)
    }
    #undef STEP

    // ---- epilogue ----
    const int cb = nb * 256 + wnn * 64;
    const int rb = mb * 256 + wmm * 128 + (lane >> 4) * 4;
    if (isUser) {
        #pragma unroll
        for (int ni = 0; ni < 4; ++ni) {
            const int col = cb + ni * 16 + fr;
            const float bv = bu[col];
            #pragma unroll
            for (int mi = 0; mi < 8; ++mi) {
                f32x4 v = acc[mi][ni];
                #pragma unroll
                for (int r = 0; r < 4; ++r) {
                    const int row = rb + mi * 16 + r;
                    Uemb[(size_t)row * LATENT + col] = f2bf(fmaxf(v[r] + bv, 0.0f));
                }
            }
        }
    } else {
        unsigned short* P = (kth == 0) ? P0 : (kth == 1) ? P1 : P2;
        #pragma unroll
        for (int ni = 0; ni < 4; ++ni) {
            const int col = cb + ni * 16 + fr;
            #pragma unroll
            for (int mi = 0; mi < 8; ++mi) {
                f32x4 v = acc[mi][ni];
                #pragma unroll
                for (int r = 0; r < 4; ++r) {
                    const int row = rb + mi * 16 + r;
                    P[(size_t)row * LATENT + col] = f2bf(v[r]);   // partial
                }
            }
        }
    }
}

// ---- Kernel 3: out[b] = sum_d U[b,d] * relu(P0+P1+P2+bi)[b,d] ----
__global__ void rowdot(const unsigned short* __restrict__ U,
                       const unsigned short* __restrict__ P0,
                       const unsigned short* __restrict__ P1,
                       const unsigned short* __restrict__ P2,
                       const float* __restrict__ bi,
                       float* __restrict__ out) {
    const int lane = threadIdx.x & 63;
    const int w    = threadIdx.x >> 6;
    const int row  = blockIdx.x * 4 + w;
    const size_t base = (size_t)row * LATENT + lane * 8;
    const uint4 uv = *(const uint4*)(U  + base);
    const uint4 p0 = *(const uint4*)(P0 + base);
    const uint4 p1 = *(const uint4*)(P1 + base);
    const uint4 p2 = *(const uint4*)(P2 + base);
    const float4 b0 = *(const float4*)(bi + lane * 8);
    const float4 b1 = *(const float4*)(bi + lane * 8 + 4);
    const float bb[8] = {b0.x, b0.y, b0.z, b0.w, b1.x, b1.y, b1.z, b1.w};
    const unsigned int* up = (const unsigned int*)&uv;
    const unsigned int* q0 = (const unsigned int*)&p0;
    const unsigned int* q1 = (const unsigned int*)&p1;
    const unsigned int* q2 = (const unsigned int*)&p2;
    float acc = 0.0f;
    #pragma unroll
    for (int q = 0; q < 4; ++q) {
        float ilo = fmaxf(bf2f(q0[q] & 0xffffu) + bf2f(q1[q] & 0xffffu)
                        + bf2f(q2[q] & 0xffffu) + bb[2 * q], 0.0f);
        float ihi = fmaxf(bf2f(q0[q] >> 16) + bf2f(q1[q] >> 16)
                        + bf2f(q2[q] >> 16) + bb[2 * q + 1], 0.0f);
        acc += bf2f(up[q] & 0xffffu) * ilo;
        acc += bf2f(up[q] >> 16)     * ihi;
    }
    #pragma unroll
    for (int off = 32; off >= 1; off >>= 1)
        acc += __shfl_xor(acc, off, 64);
    if (lane == 0) out[row] = acc;
}

extern "C" void kernel_launch(void* const* d_in, const int* in_sizes, int n_in,
                              void* d_out, int out_size, void* d_ws, size_t ws_size,
                              hipStream_t stream) {
    const float* x  = (const float*)d_in[0];
    const float* Wu = (const float*)d_in[1];
    const float* bu = (const float*)d_in[2];
    const float* Wi = (const float*)d_in[3];
    const float* bi = (const float*)d_in[4];
    float* out = (float*)d_out;

    unsigned short* WuB  = (unsigned short*)d_ws;                 // 512*3712 bf16
    unsigned short* WiB  = WuB + (size_t)LATENT * KPAD_U;         // 512*6144 bf16
    unsigned short* Uemb = WiB + (size_t)LATENT * KPAD_I;         // 8192*512 bf16
    unsigned short* P0   = Uemb + (size_t)BATCH * LATENT;
    unsigned short* P1   = P0   + (size_t)BATCH * LATENT;
    unsigned short* P2   = P1   + (size_t)BATCH * LATENT;

    convert_w<<<dim3((KPAD_U + 255) / 256, LATENT), 256, 0, stream>>>(Wu, WuB, USER_DIM, KPAD_U);
    convert_w<<<dim3((KPAD_I + 255) / 256, LATENT), 256, 0, stream>>>(Wi, WiB, ITEM_DIM, KPAD_I);

    // 256 blocks = exactly 1 per CU: 64 user (116 steps) + 192 item thirds (64 steps)
    gemm_fused<<<256, 512, 0, stream>>>(x, WuB, bu, WiB, Uemb, P0, P1, P2);

    rowdot<<<BATCH / 4, 256, 0, stream>>>(Uemb, P0, P1, P2, bi, out);
}